// Round 3
// baseline (477.170 us; speedup 1.0000x reference)
//
#include <hip/hip_runtime.h>

#define BATCH 512
#define NNODE 200
#define CIN   200
#define HID   128
#define IPAD  232   // LDS/W1T row stride: 464B rows, 16B-aligned, stride%32dw=20 -> ~2-way read aliasing
#define KCH   7     // 7 K-chunks of 32 (cover 224 >= 200)

typedef __attribute__((ext_vector_type(4))) float  f32x4;
typedef __attribute__((ext_vector_type(8))) short  sh8;
typedef __attribute__((ext_vector_type(4))) short  sh4;
typedef __attribute__((ext_vector_type(8))) __bf16 bf16x8;

__device__ __forceinline__ short f2bf(float x) {
  union { float f; unsigned u; } v; v.f = x;
  unsigned r = v.u + 0x7FFFu + ((v.u >> 16) & 1u);   // RNE
  return (short)(r >> 16);
}
__device__ __forceinline__ f32x4 mfma16(sh8 a, sh8 b, f32x4 c) {
  return __builtin_amdgcn_mfma_f32_16x16x32_bf16(
      __builtin_bit_cast(bf16x8, a), __builtin_bit_cast(bf16x8, b), c, 0, 0, 0);
}

// ---------- K0: W1 [200][128] fp32 -> W1T [128][232] bf16 (cols [200,232) zeroed) ----------
__global__ void k_w1t(const float* __restrict__ W1, short* __restrict__ W1T) {
  int idx = blockIdx.x * 256 + threadIdx.x;
  if (idx < CIN * HID) {                       // coalesced read of W1
    int c = idx >> 7, f = idx & 127;
    W1T[f * IPAD + c] = f2bf(W1[idx]);
  } else {
    int q = idx - CIN * HID;                   // zero pad cols [200,232)
    if (q < HID * (IPAD - CIN)) {
      int f = q / (IPAD - CIN), c = CIN + q % (IPAD - CIN);
      W1T[f * IPAD + c] = 0;
    }
  }
}

// ---------- K_fused: one block per batch. 512 threads (8 waves). ----------
// phase A: yT[f][i] = (x @ W1)^T into LDS (MFMA, x/W1T from global)
// pass 1 : D[f][j] = sum_i yT[f][i]*A'[i][j] (adj read directly as int, diag folded)
//          h = relu(D + b1); g[j] = h @ W2 (fp32); rowdeg via shfl+LDS-atomic
// epilog : out[b] = b2 + sum_j g[j]*(1+e2+rowdeg[j]) / N
__global__ __launch_bounds__(512) void k_fused(const float* __restrict__ x,
                                               const int* __restrict__ adj,
                                               const short* __restrict__ W1T,
                                               const float* __restrict__ b1,
                                               const float* __restrict__ W2,
                                               const float* __restrict__ b2,
                                               const float* __restrict__ eps1p,
                                               const float* __restrict__ eps2p,
                                               float* __restrict__ out) {
  __shared__ short yT[HID][IPAD];   // 59,392 B
  __shared__ float g2[2][NNODE];    // 1,600 B
  __shared__ int   rsum[224];       //   896 B
  __shared__ float b1s[HID];        //   512 B
  __shared__ float W2s[HID][2];     // 1,024 B
  __shared__ float red[16];         //    64 B   -> total 63,488 B (2 blocks/CU)

  const int b = blockIdx.x, tid = threadIdx.x;
  const int wave = tid >> 6, lane = tid & 63, lq = lane >> 4, lm = lane & 15;

  // ---- phase 0: init small LDS (disjoint from phase-A stores; one barrier covers all) ----
  for (int i = tid; i < HID * 16; i += 512) {            // zero yT[:, 200:232)
    int f = i >> 4, o = i & 15;
    *(int*)&yT[f][200 + 2 * o] = 0;
  }
  if (tid < 224) rsum[tid] = 0;
  if (tid < HID) { b1s[tid] = b1[tid]; W2s[tid][0] = W2[tid * 2]; W2s[tid][1] = W2[tid * 2 + 1]; }
  const float e1 = eps1p[0], e2 = eps2p[0];
  const short c_one = 0x3F80;                            // bf16(1.0)
  const short c_d0 = f2bf(1.f + e1);                     // diag, adj==0
  const short c_d1 = f2bf(2.f + e1);                     // diag, adj==1

  // ---- phase A: yT = (x @ W1)^T into LDS ----
  const float* xb = x + (size_t)b * NNODE * CIN;
  for (int mt = wave; mt < 13; mt += 8) {
    const int Mbase = mt * 16;
    const int row = min(Mbase + lm, NNODE - 1);
    const float* xr = xb + (size_t)row * CIN;

    sh8 af[KCH];                                         // A-frags held across f-tiles
#pragma unroll
    for (int k = 0; k < KCH; ++k) {
      const int c0 = k * 32 + lq * 8;
      f32x4 p0 = {0.f,0.f,0.f,0.f}, p1 = {0.f,0.f,0.f,0.f};
      if (c0 < CIN) { p0 = *(const f32x4*)(xr + c0); p1 = *(const f32x4*)(xr + c0 + 4); }
      sh8 a;
#pragma unroll
      for (int j = 0; j < 4; ++j) { a[j] = f2bf(p0[j]); a[4 + j] = f2bf(p1[j]); }
      af[k] = a;
    }

    for (int ft = 0; ft < 8; ++ft) {
      const int fb = ft * 16;
      const short* wrow = W1T + (size_t)(fb + lm) * IPAD;
      f32x4 acc = {0.f,0.f,0.f,0.f};
#pragma unroll
      for (int k = 0; k < KCH; ++k)
        acc = mfma16(af[k], *(const sh8*)(wrow + k * 32 + lq * 8), acc);
      const int i0 = Mbase + lq * 4;                     // D: n=lm->f, m=lq*4+r->i
      if (i0 + 3 < NNODE) {                              // i>=200 stays zero
        sh4 st;
#pragma unroll
        for (int r = 0; r < 4; ++r) st[r] = f2bf(acc[r]);
        *(sh4*)&yT[fb + lm][i0] = st;
      }
    }
  }
  __syncthreads();

  // ---- pass 1: aggregate + MLP1 + ReLU + W2 projection; rowdeg on the side ----
  const int* adjb = adj + (size_t)b * NNODE * NNODE;
  for (int jt = wave; jt < 13; jt += 8) {
    const int j = jt * 16 + lm;
    const bool jok = (j < NNODE);

    sh8 bf[KCH];                                         // B[k=i][n=j] from raw adj
#pragma unroll
    for (int k = 0; k < KCH; ++k) {
      sh8 frag;
#pragma unroll
      for (int r = 0; r < 8; ++r) {
        const int i = k * 32 + lq * 8 + r;
        int v = 0;
        if (i < NNODE && jok) v = adjb[i * NNODE + j];   // 64B-coalesced per quarter-wave
        frag[r] = (i == j) ? (v ? c_d1 : c_d0) : (v ? c_one : (short)0);
        int cnt = v;                                     // raw rowdeg partial over 16 j's
        cnt += __shfl_xor(cnt, 1);
        cnt += __shfl_xor(cnt, 2);
        cnt += __shfl_xor(cnt, 4);
        cnt += __shfl_xor(cnt, 8);
        if (lm == 0 && i < NNODE) atomicAdd(&rsum[i], cnt);
      }
      bf[k] = frag;
    }

    float ga = 0.f, gb = 0.f;
    for (int ft = 0; ft < 8; ++ft) {
      const int fb2 = ft * 16;
      f32x4 acc = {0.f,0.f,0.f,0.f};
#pragma unroll
      for (int k = 0; k < KCH; ++k)
        acc = mfma16(*(const sh8*)&yT[fb2 + lm][k * 32 + lq * 8], bf[k], acc);
#pragma unroll
      for (int r = 0; r < 4; ++r) {
        const int f = fb2 + lq * 4 + r;                  // D[m=f][n=j]; diag has (1+e1)
        float h = fmaxf(acc[r] + b1s[f], 0.f);
        ga += h * W2s[f][0];
        gb += h * W2s[f][1];
      }
    }
    ga += __shfl_xor(ga, 16); ga += __shfl_xor(ga, 32);  // reduce 4 lq groups
    gb += __shfl_xor(gb, 16); gb += __shfl_xor(gb, 32);
    if (lane < 16 && jok) { g2[0][j] = ga; g2[1][j] = gb; }
  }
  __syncthreads();

  // ---- epilogue: out = b2 + (1/N) sum_j (1+e2+rowdeg_j) * g[j] ----
  float v0 = 0.f, v1 = 0.f;
  if (tid < NNODE) {
    const float w = 1.f + e2 + (float)rsum[tid];
    v0 = w * g2[0][tid];
    v1 = w * g2[1][tid];
  }
#pragma unroll
  for (int d = 1; d < 64; d <<= 1) { v0 += __shfl_xor(v0, d); v1 += __shfl_xor(v1, d); }
  if (lane == 0) { red[wave * 2] = v0; red[wave * 2 + 1] = v1; }
  __syncthreads();
  if (tid == 0) {
    float s0 = 0.f, s1 = 0.f;
#pragma unroll
    for (int w = 0; w < 8; ++w) { s0 += red[w * 2]; s1 += red[w * 2 + 1]; }
    out[b * 2 + 0] = b2[0] + s0 * (1.f / NNODE);
    out[b * 2 + 1] = b2[1] + s1 * (1.f / NNODE);
  }
}

extern "C" void kernel_launch(void* const* d_in, const int* in_sizes, int n_in,
                              void* d_out, int out_size, void* d_ws, size_t ws_size,
                              hipStream_t stream) {
  const float* x    = (const float*)d_in[0];
  const int*   adj  = (const int*)d_in[1];
  const float* W1   = (const float*)d_in[2];
  const float* b1   = (const float*)d_in[3];
  const float* W2   = (const float*)d_in[4];
  const float* b2   = (const float*)d_in[5];
  const float* eps1 = (const float*)d_in[6];
  const float* eps2 = (const float*)d_in[7];
  float* out = (float*)d_out;

  short* W1T = (short*)d_ws;                             // [128][232] bf16, only ws use

  k_w1t  <<<(HID * IPAD + 255) / 256, 256, 0, stream>>>(W1, W1T);
  k_fused<<<BATCH, 512, 0, stream>>>(x, adj, W1T, b1, W2, b2, eps1, eps2, out);
}

// Round 4
// 396.757 us; speedup vs baseline: 1.2027x; 1.2027x over previous
//
#include <hip/hip_runtime.h>

#define BATCH 512
#define NNODE 200
#define CIN   200
#define HID   128
#define IPAD  232   // LDS row stride: 464B rows, 16B-aligned
#define KCH   7     // 7 K-chunks of 32 (cover 224 >= 200)

typedef __attribute__((ext_vector_type(4))) float  f32x4;
typedef __attribute__((ext_vector_type(8))) short  sh8;
typedef __attribute__((ext_vector_type(4))) short  sh4;
typedef __attribute__((ext_vector_type(8))) __bf16 bf16x8;

__device__ __forceinline__ short f2bf(float x) {
  union { float f; unsigned u; } v; v.f = x;
  unsigned r = v.u + 0x7FFFu + ((v.u >> 16) & 1u);   // RNE
  return (short)(r >> 16);
}
__device__ __forceinline__ f32x4 mfma16(sh8 a, sh8 b, f32x4 c) {
  return __builtin_amdgcn_mfma_f32_16x16x32_bf16(
      __builtin_bit_cast(bf16x8, a), __builtin_bit_cast(bf16x8, b), c, 0, 0, 0);
}

// ---------- K0: W1 [200][128] fp32 -> W1T [128][232] bf16 (cols [200,232) zeroed) ----------
__global__ void k_w1t(const float* __restrict__ W1, short* __restrict__ W1T) {
  int idx = blockIdx.x * 256 + threadIdx.x;
  if (idx < CIN * HID) {
    int c = idx >> 7, f = idx & 127;
    W1T[f * IPAD + c] = f2bf(W1[idx]);
  } else {
    int q = idx - CIN * HID;
    if (q < HID * (IPAD - CIN)) {
      int f = q / (IPAD - CIN), c = CIN + q % (IPAD - CIN);
      W1T[f * IPAD + c] = 0;
    }
  }
}

// ---------- K_main: one block per batch, 512 threads. ----------
// phase A: yT = (x@W1)^T into LDS (MFMA)
// pass 1 : D[f][j] = sum_i yT[f][i]*A'[i][j], A' = adj + (1+e1)I, frags RETAINED in regs
//          h = relu(D+b1); g[j] = h@W2 (fp32, kept in regs); per-tile sum(g) -> LDS atomics
// swap   : yT rows 0..15 overwritten with gT (bf16, rows 2..15 zero)
// pass 2 : D2[c][j] = sum_i gT[c][i]*A'[i][j] using retained frags; sum over j -> sums[2..3]
// epilog : out = b2 + (sumagg + (e2-e1)*sumg)/N
__global__ __launch_bounds__(512) void k_main(const float* __restrict__ x,
                                              const int* __restrict__ adj,
                                              const short* __restrict__ W1T,
                                              const float* __restrict__ b1,
                                              const float* __restrict__ W2,
                                              const float* __restrict__ b2,
                                              const float* __restrict__ eps1p,
                                              const float* __restrict__ eps2p,
                                              float* __restrict__ out) {
  __shared__ short yT[HID][IPAD];   // 59,392 B (reused as gT[16][IPAD] for pass 2)
  __shared__ float gsm[2][NNODE];   //  1,600 B
  __shared__ float b1s[HID];        //    512 B
  __shared__ float W2s[HID][2];     //  1,024 B
  __shared__ float sums[4];         // sumg0, sumg1, sumagg0, sumagg1

  const int b = blockIdx.x, tid = threadIdx.x;
  const int wave = tid >> 6, lane = tid & 63, lq = lane >> 4, lm = lane & 15;

  // ---- init ----
  for (int i = tid; i < HID * 16; i += 512) {            // zero yT[:, 200:232)
    int f = i >> 4, o = i & 15;
    *(int*)&yT[f][200 + 2 * o] = 0;
  }
  if (tid < HID) { b1s[tid] = b1[tid]; W2s[tid][0] = W2[tid * 2]; W2s[tid][1] = W2[tid * 2 + 1]; }
  if (tid < 4) sums[tid] = 0.f;
  const float e1 = eps1p[0], e2 = eps2p[0];
  const short c_one = 0x3F80;                            // bf16(1.0)
  const short c_d0 = f2bf(1.f + e1);                     // diag, adj==0
  const short c_d1 = f2bf(2.f + e1);                     // diag, adj==1

  // ---- phase A: yT = (x @ W1)^T into LDS ----
  const float* xb = x + (size_t)b * NNODE * CIN;
  for (int mt = wave; mt < 13; mt += 8) {
    const int Mbase = mt * 16;
    const int row = min(Mbase + lm, NNODE - 1);
    const float* xr = xb + (size_t)row * CIN;

    sh8 af[KCH];
#pragma unroll
    for (int k = 0; k < KCH; ++k) {
      const int c0 = k * 32 + lq * 8;
      f32x4 p0 = {0.f,0.f,0.f,0.f}, p1 = {0.f,0.f,0.f,0.f};
      if (c0 < CIN) { p0 = *(const f32x4*)(xr + c0); p1 = *(const f32x4*)(xr + c0 + 4); }
      sh8 a;
#pragma unroll
      for (int j = 0; j < 4; ++j) { a[j] = f2bf(p0[j]); a[4 + j] = f2bf(p1[j]); }
      af[k] = a;
    }
    for (int ft = 0; ft < 8; ++ft) {
      const int fb = ft * 16;
      const short* wrow = W1T + (size_t)(fb + lm) * IPAD;
      f32x4 acc = {0.f,0.f,0.f,0.f};
#pragma unroll
      for (int k = 0; k < KCH; ++k)
        acc = mfma16(af[k], *(const sh8*)(wrow + k * 32 + lq * 8), acc);
      const int i0 = Mbase + lq * 4;                     // D: n=lm->f, m=lq*4+r->i
      if (i0 + 3 < NNODE) {
        sh4 st;
#pragma unroll
        for (int r = 0; r < 4; ++r) st[r] = f2bf(acc[r]);
        *(sh4*)&yT[fb + lm][i0] = st;
      }
    }
  }
  __syncthreads();

  // ---- pass 1 (frags retained; NO per-element cross-lane ops) ----
  const int* adjb = adj + (size_t)b * NNODE * NNODE;
  const int jt0 = wave, jt1 = wave + 8;                  // 13 tiles over 8 waves
  sh8 keep0[KCH], keep1[KCH];

  auto pass1 = [&](int jt, sh8* keep) {
    const int j = jt * 16 + lm;
    const bool jok = (j < NNODE);
#pragma unroll
    for (int k = 0; k < KCH; ++k) {
      sh8 frag;
#pragma unroll
      for (int r = 0; r < 8; ++r) {
        const int i = k * 32 + lq * 8 + r;
        int v = 0;
        if (i < NNODE && jok) v = adjb[i * NNODE + j];   // 64B-coalesced per quarter-wave
        frag[r] = (i == j) ? (v ? c_d1 : c_d0) : (v ? c_one : (short)0);
      }
      keep[k] = frag;
    }
    float ga = 0.f, gb = 0.f;
    for (int ft = 0; ft < 8; ++ft) {
      const int fb = ft * 16;
      f32x4 acc = {0.f,0.f,0.f,0.f};
#pragma unroll
      for (int k = 0; k < KCH; ++k)
        acc = mfma16(*(const sh8*)&yT[fb + lm][k * 32 + lq * 8], keep[k], acc);
#pragma unroll
      for (int r = 0; r < 4; ++r) {
        const int f = fb + lq * 4 + r;                   // D[m=f][n=j], diag has (1+e1)
        float h = fmaxf(acc[r] + b1s[f], 0.f);
        ga += h * W2s[f][0];
        gb += h * W2s[f][1];
      }
    }
    ga += __shfl_xor(ga, 16); ga += __shfl_xor(ga, 32);  // full f-sum -> every lane has g[j=lm]
    gb += __shfl_xor(gb, 16); gb += __shfl_xor(gb, 32);
    if (lane < 16 && jok) { gsm[0][j] = ga; gsm[1][j] = gb; }
    float ta = (lane < 16 && jok) ? ga : 0.f;            // once-per-tile sum(g)
    float tb = (lane < 16 && jok) ? gb : 0.f;
#pragma unroll
    for (int d = 1; d < 16; d <<= 1) { ta += __shfl_xor(ta, d); tb += __shfl_xor(tb, d); }
    if (lane == 0) { atomicAdd(&sums[0], ta); atomicAdd(&sums[1], tb); }
  };

  pass1(jt0, keep0);
  if (jt1 < 13) pass1(jt1, keep1);
  __syncthreads();                                       // all pass-1 yT reads done

  // ---- swap: yT rows 0..15 -> gT (rows 2..15 zero) ----
  for (int i = tid; i < 16 * IPAD / 2; i += 512) ((int*)yT)[i] = 0;
  __syncthreads();
  if (tid < NNODE) { yT[0][tid] = f2bf(gsm[0][tid]); yT[1][tid] = f2bf(gsm[1][tid]); }
  __syncthreads();

  // ---- pass 2: sum_j (A'^T g)_j via retained frags ----
  auto pass2 = [&](int jt, const sh8* keep) {
    const int j = jt * 16 + lm;
    const bool jok = (j < NNODE);
    f32x4 acc = {0.f,0.f,0.f,0.f};
#pragma unroll
    for (int k = 0; k < KCH; ++k)
      acc = mfma16(*(const sh8*)&yT[lm][k * 32 + lq * 8], keep[k], acc);  // A[m=c][k=i]
    float v0 = (lq == 0 && jok) ? acc[0] : 0.f;          // D2[c=0][j=lm]
    float v1 = (lq == 0 && jok) ? acc[1] : 0.f;          // D2[c=1][j=lm]
#pragma unroll
    for (int d = 1; d < 16; d <<= 1) { v0 += __shfl_xor(v0, d); v1 += __shfl_xor(v1, d); }
    if (lane == 0) { atomicAdd(&sums[2], v0); atomicAdd(&sums[3], v1); }
  };

  pass2(jt0, keep0);
  if (jt1 < 13) pass2(jt1, keep1);
  __syncthreads();

  if (tid == 0) {
    // sums[2..3] = sum_j agg2 + (1+e1)*sum(g); want sum_j[(1+e2)g + agg2]
    out[b * 2 + 0] = b2[0] + (sums[2] + (e2 - e1) * sums[0]) * (1.f / NNODE);
    out[b * 2 + 1] = b2[1] + (sums[3] + (e2 - e1) * sums[1]) * (1.f / NNODE);
  }
}

extern "C" void kernel_launch(void* const* d_in, const int* in_sizes, int n_in,
                              void* d_out, int out_size, void* d_ws, size_t ws_size,
                              hipStream_t stream) {
  const float* x    = (const float*)d_in[0];
  const int*   adj  = (const int*)d_in[1];
  const float* W1   = (const float*)d_in[2];
  const float* b1   = (const float*)d_in[3];
  const float* W2   = (const float*)d_in[4];
  const float* b2   = (const float*)d_in[5];
  const float* eps1 = (const float*)d_in[6];
  const float* eps2 = (const float*)d_in[7];
  float* out = (float*)d_out;

  short* W1T = (short*)d_ws;                             // [128][232] bf16

  k_w1t <<<(HID * IPAD + 255) / 256, 256, 0, stream>>>(W1, W1T);
  k_main<<<BATCH, 512, 0, stream>>>(x, adj, W1T, b1, W2, b2, eps1, eps2, out);
}